// Round 11
// baseline (285.275 us; speedup 1.0000x reference)
//
#include <hip/hip_runtime.h>
#include <math.h>

#define SCALING 0.125f

typedef __attribute__((ext_vector_type(8))) short short8;
typedef __attribute__((ext_vector_type(4))) float f32x4;

// round-to-nearest-even fp32 -> bf16
static __device__ __forceinline__ unsigned short bf16r(float x) {
  unsigned int u = __float_as_uint(x);
  u += 0x7fffu + ((u >> 16) & 1u);
  return (unsigned short)(u >> 16);
}
static __device__ __forceinline__ float bf16f(unsigned short h) {
  return __uint_as_float(((unsigned int)h) << 16);
}
// pack two fp32 -> bf16x2 via v_perm_b32 merge
static __device__ __forceinline__ unsigned int pk_bf16(float lo, float hi) {
  unsigned int ua = __float_as_uint(lo);
  unsigned int ub = __float_as_uint(hi);
  ua += 0x7fffu + ((ua >> 16) & 1u);
  ub += 0x7fffu + ((ub >> 16) & 1u);
  return __builtin_amdgcn_perm(ub, ua, 0x07060302u);
}
// fp32x4 -> bf16 hi + residual lo
static __device__ __forceinline__ void split4(float4 x, ushort4& h, ushort4& l) {
  h.x = bf16r(x.x); l.x = bf16r(x.x - bf16f(h.x));
  h.y = bf16r(x.y); l.y = bf16r(x.y - bf16f(h.y));
  h.z = bf16r(x.z); l.z = bf16r(x.z - bf16f(h.z));
  h.w = bf16r(x.w); l.w = bf16r(x.w - bf16f(h.w));
}
union U4S8 { uint4 u; short8 s; };

// async global->LDS, 16B per lane (wave-uniform LDS base + lane*16; per-lane
// global address). Tracked by vmcnt; __syncthreads drains it (m97 semantics).
static __device__ __forceinline__ void gload16(const unsigned short* g,
                                               unsigned short* l) {
  __builtin_amdgcn_global_load_lds(
      (const __attribute__((address_space(1))) void*)(g),
      (__attribute__((address_space(3))) void*)(l), 16, 0, 0);
}

// ---------------------------------------------------------------------------
// Kernel P: one-shot hi/lo bf16 split of all loop-invariant GEMM operands.
// R3-verbatim.
// ---------------------------------------------------------------------------
__global__ __launch_bounds__(256)
void prep_kernel(const float* __restrict__ query,
                 const float* __restrict__ key,
                 const float* __restrict__ value,
                 const float* __restrict__ W,
                 const float* __restrict__ out_w,
                 unsigned short* __restrict__ Xh,
                 unsigned short* __restrict__ Xl,
                 unsigned short* __restrict__ Wh,
                 unsigned short* __restrict__ Wl,
                 unsigned short* __restrict__ Owh,
                 unsigned short* __restrict__ Owl) {
  const int t = blockIdx.x * 256 + threadIdx.x;  // 0..655359
  const int e = t * 4;
  const float* __restrict__ src;
  unsigned short *dh, *dl;
  if (e < 1572864) {               // query|key|value: 3 x 524288 floats
    const int g = e >> 19, j = e & 524287;
    src = (g == 0 ? query : g == 1 ? key : value) + j;
    dh = Xh + e; dl = Xl + e;
  } else if (e < 2359296) {        // W: 1536x512
    const int j = e - 1572864;
    src = W + j; dh = Wh + j; dl = Wl + j;
  } else {                         // out_w: 512x512
    const int j = e - 2359296;
    src = out_w + j; dh = Owh + j; dl = Owl + j;
  }
  const float4 v = *(const float4*)src;
  ushort4 hh, ll;
  split4(v, hh, ll);
  *(ushort4*)dh = hh;
  *(ushort4*)dl = ll;
}

// ---------------------------------------------------------------------------
// Kernel A v6: R9-verbatim (gload_lds direct staging, double buffer, one
// barrier per K-step, rule-#21 both-sides swizzle). Measured best.
// ---------------------------------------------------------------------------
__global__ __launch_bounds__(256)
void projmm_kernel(const unsigned short* __restrict__ Xh,
                   const unsigned short* __restrict__ Xl,
                   const unsigned short* __restrict__ Wh,
                   const unsigned short* __restrict__ Wl,
                   const float* __restrict__ bias,
                   float* __restrict__ qh, float* __restrict__ kh,
                   unsigned short* __restrict__ vh) {
  __shared__ __align__(16) unsigned short S[2][12288];
  const int n0 = blockIdx.x * 32;  // 0..1504
  const int g = n0 >> 9;           // 0=q,1=k,2=v (32-tiles never straddle 512)
  const unsigned short* __restrict__ Xgh = Xh + g * 524288;
  const unsigned short* __restrict__ Xgl = Xl + g * 524288;
  const int m0 = blockIdx.y * 64;
  const int tid = threadIdx.x;
  const int w = tid >> 6, lane = tid & 63;
  const int quad = lane >> 4, n15 = lane & 15;
  const int lrow = lane >> 3;                       // 0..7 (chunk-local row)
  const int colOff = ((lane & 7) ^ lrow) * 8;       // inverse-swz source col

  // per-wave 6 staging chunks: global base (sans k0) + LDS offset
  const unsigned short* gb[6];
  int lo[6];
#pragma unroll
  for (int j = 0; j < 6; ++j) {
    const int c = w * 6 + j;
    const unsigned short* gsrc;
    int off, grow;
    if (c < 8)       { gsrc = Xgh; off = c * 512;              grow = m0 + c * 8; }
    else if (c < 16) { gsrc = Xgl; off = 4096 + (c - 8) * 512;  grow = m0 + (c - 8) * 8; }
    else if (c < 20) { gsrc = Wh;  off = 8192 + (c - 16) * 512; grow = n0 + (c - 16) * 8; }
    else             { gsrc = Wl;  off = 10240 + (c - 20) * 512; grow = n0 + (c - 20) * 8; }
    gb[j] = gsrc + (size_t)(grow + lrow) * 512 + colOff;
    lo[j] = off;
  }

  f32x4 acc[2];
#pragma unroll
  for (int nt = 0; nt < 2; ++nt) acc[nt] = (f32x4){0.f, 0.f, 0.f, 0.f};

  // prologue: stage k-tile 0 into side 0
#pragma unroll
  for (int j = 0; j < 6; ++j) gload16(gb[j], &S[0][lo[j]]);
  __syncthreads();

  const int rA = w * 16 + n15;
  const int swz = n15 & 7;
  int side = 0;
  for (int k0 = 0; k0 < 512; k0 += 64) {
    if (k0 + 64 < 512) {
      const int ns = side ^ 1;
#pragma unroll
      for (int j = 0; j < 6; ++j) gload16(gb[j] + k0 + 64, &S[ns][lo[j]]);
    }
#pragma unroll
    for (int kk = 0; kk < 2; ++kk) {
      const int gA0 = ((kk * 4 + quad) ^ swz) * 8;
      short8 ah = *(const short8*)&S[side][rA * 64 + gA0];
      short8 al = *(const short8*)&S[side][4096 + rA * 64 + gA0];
#pragma unroll
      for (int nt = 0; nt < 2; ++nt) {
        const int rB = nt * 16 + n15;
        short8 bh = *(const short8*)&S[side][8192 + rB * 64 + gA0];
        short8 bl = *(const short8*)&S[side][10240 + rB * 64 + gA0];
        acc[nt] = __builtin_amdgcn_mfma_f32_16x16x32_bf16(ah, bh, acc[nt], 0, 0, 0);
        acc[nt] = __builtin_amdgcn_mfma_f32_16x16x32_bf16(ah, bl, acc[nt], 0, 0, 0);
        acc[nt] = __builtin_amdgcn_mfma_f32_16x16x32_bf16(al, bh, acc[nt], 0, 0, 0);
      }
    }
    if (k0 + 64 < 512) {
      __syncthreads();  // drains vmcnt (stage done) + all reads of 'side' done
      side ^= 1;
    }
  }

#pragma unroll
  for (int nt = 0; nt < 2; ++nt) {
    const int j = n0 + nt * 16 + n15;
    const int jj = j & 511;
    const int head = jj >> 6;
    const int hd = jj & 63;
    const float bj = bias[j];
#pragma unroll
    for (int r = 0; r < 4; ++r) {
      const int row = m0 + w * 16 + quad * 4 + r;
      const int t = row >> 3;
      const int batch = row & 7;
      const int i = batch * 8 + head;
      const int idx = ((i << 7) + t) * 64 + hd;
      const float val = acc[nt][r] + bj;
      if (g == 0)      qh[idx] = val * SCALING;
      else if (g == 1) kh[idx] = val;
      else             vh[idx] = bf16r(val);
    }
  }
}

// ---------------------------------------------------------------------------
// Kernel B v6: R10 (NT bias + XCD swizzle) with ONE structural change:
// Vs LDS staging ELIMINATED. vh is bf16 [c][t] == exact MFMA A-fragment
// layout, and post-swizzle each head's 16KB V-slice is L2-hot (shared by
// all 128 blocks on its XCD) -> A-frags load DIRECT from global (m169:
// staging L2-fit data is pure overhead). Ks staging/barrier structure and
// all arithmetic unchanged -> absmax exact. LDS 77824 -> 40960 B ->
// 3 blocks/CU (12 waves, +50% TLP to cover the per-head latency).
// ---------------------------------------------------------------------------
__global__ __launch_bounds__(256, 3)
void score_kernel(const float* __restrict__ qh,
                  const float* __restrict__ kh,
                  const unsigned short* __restrict__ vh,
                  const float* __restrict__ cbias,
                  unsigned short* __restrict__ attn_h,
                  unsigned short* __restrict__ attn_l) {
  __shared__ __align__(16) unsigned short Ks[2][128 * 72];
  __shared__ float rowS[8 * 128];  // fused rows, then softmax weights

  const int d = blockIdx.x;
  const int ab = ((d & 7) << 7) | (d >> 3);  // batch = d&7 -> XCD-local batch
  const int batch = ab >> 7;
  const int a = ab & 127;
  const int tid = threadIdx.x;
  const int w = tid >> 6;
  const int lane = tid & 63;
  const int quad = lane >> 4;
  const int n15 = lane & 15;
  const int col8 = (tid & 7) * 8;

  // bias fragment preload (head-invariant coords; verified mapping) — NT loads
  const float* __restrict__ bp = cbias + (size_t)ab * 16384;
  f32x4 biasReg[8][2];
#pragma unroll
  for (int ic = 0; ic < 8; ++ic)
#pragma unroll
    for (int jb = 0; jb < 2; ++jb) {
      const int b = w * 32 + jb * 16 + n15;
      biasReg[ic][jb] = __builtin_nontemporal_load(
          (const f32x4*)&bp[b * 128 + ic * 16 + quad * 4]);
    }

  // ---- prologue: pack head 0's k*q into Ks[0] ----
  {
    const int i = batch * 8;
    const float* __restrict__ kb = kh + (size_t)i * 8192;
    const float* __restrict__ qa = qh + ((size_t)i * 128 + a) * 64;
    f32x4 q0 = *(const f32x4*)&qa[col8];
    f32x4 q1 = *(const f32x4*)&qa[col8 + 4];
#pragma unroll
    for (int j = 0; j < 4; ++j) {
      const int gg = j * 256 + tid;
      const int row = gg >> 3;
      f32x4 k0 = *(const f32x4*)&kb[8 * gg];
      f32x4 k1 = *(const f32x4*)&kb[8 * gg + 4];
      k0 *= q0;
      k1 *= q1;
      uint4 pk;
      pk.x = pk_bf16(k0[0], k0[1]); pk.y = pk_bf16(k0[2], k0[3]);
      pk.z = pk_bf16(k1[0], k1[1]); pk.w = pk_bf16(k1[2], k1[3]);
      *(uint4*)&Ks[0][row * 72 + col8] = pk;
    }
  }
  __syncthreads();

  for (int h = 0; h < 8; ++h) {
    const int buf = h & 1;
    const int i = batch * 8 + h;
    const unsigned short* __restrict__ vb = vh + (size_t)i * 8192;

    // ---- issue next head's k/q loads (in flight during MFMA)
    f32x4 kreg[4][2];
    f32x4 qn0, qn1;
    if (h < 7) {
      const int in = i + 1;
      const float* __restrict__ kb = kh + (size_t)in * 8192;
      const float* __restrict__ qa = qh + ((size_t)in * 128 + a) * 64;
      qn0 = *(const f32x4*)&qa[col8];
      qn1 = *(const f32x4*)&qa[col8 + 4];
#pragma unroll
      for (int j = 0; j < 4; ++j) {
        const int gg = j * 256 + tid;
        kreg[j][0] = *(const f32x4*)&kb[8 * gg];
        kreg[j][1] = *(const f32x4*)&kb[8 * gg + 4];
      }
    }

    // ---- B-fragments from Ks[buf]
    short8 bf[2][2];
#pragma unroll
    for (int jb = 0; jb < 2; ++jb)
#pragma unroll
      for (int kk = 0; kk < 2; ++kk)
        bf[jb][kk] = *(const short8*)&Ks[buf][(w * 32 + jb * 16 + n15) * 72 +
                                             kk * 32 + quad * 8];

    // ---- MFMA: S^T[c,b]; A-frags DIRECT from global (L2-hot 16KB slice);
    //      bias as C-init (R1-verified)
    f32x4 acc[8][2];
#pragma unroll
    for (int ic = 0; ic < 8; ++ic) {
      U4S8 ua0, ua1;
      ua0.u = *(const uint4*)&vb[(ic * 16 + n15) * 64 + quad * 8];
      ua1.u = *(const uint4*)&vb[(ic * 16 + n15) * 64 + 32 + quad * 8];
      const short8 a0 = ua0.s, a1 = ua1.s;
      acc[ic][0] = __builtin_amdgcn_mfma_f32_16x16x32_bf16(a0, bf[0][0], biasReg[ic][0], 0, 0, 0);
      acc[ic][0] = __builtin_amdgcn_mfma_f32_16x16x32_bf16(a1, bf[0][1], acc[ic][0], 0, 0, 0);
      acc[ic][1] = __builtin_amdgcn_mfma_f32_16x16x32_bf16(a0, bf[1][0], biasReg[ic][1], 0, 0, 0);
      acc[ic][1] = __builtin_amdgcn_mfma_f32_16x16x32_bf16(a1, bf[1][1], acc[ic][1], 0, 0, 0);
    }

    // ---- pack + store next head's K staging into the other buffer
    if (h < 7) {
      const int nb = buf ^ 1;
#pragma unroll
      for (int j = 0; j < 4; ++j) {
        const int gg = j * 256 + tid;
        const int row = gg >> 3;
        kreg[j][0] *= qn0;
        kreg[j][1] *= qn1;
        uint4 pk;
        pk.x = pk_bf16(kreg[j][0][0], kreg[j][0][1]);
        pk.y = pk_bf16(kreg[j][0][2], kreg[j][0][3]);
        pk.z = pk_bf16(kreg[j][1][0], kreg[j][1][1]);
        pk.w = pk_bf16(kreg[j][1][2], kreg[j][1][3]);
        *(uint4*)&Ks[nb][row * 72 + col8] = pk;
      }
    }

    // ---- epilogue: mean/max over c (bias already in acc) -> rowS (LDS)
    float fsum[2] = {0.f, 0.f};
    float fmx[2] = {-INFINITY, -INFINITY};
#pragma unroll
    for (int ic = 0; ic < 8; ++ic)
#pragma unroll
      for (int jb = 0; jb < 2; ++jb) {
        const float v0 = acc[ic][jb][0];
        const float v1 = acc[ic][jb][1];
        const float v2 = acc[ic][jb][2];
        const float v3 = acc[ic][jb][3];
        fsum[jb] += (v0 + v1) + (v2 + v3);
        fmx[jb] = fmaxf(fmx[jb], fmaxf(fmaxf(v0, v1), fmaxf(v2, v3)));
      }
#pragma unroll
    for (int off = 16; off <= 32; off <<= 1) {
#pragma unroll
      for (int jb = 0; jb < 2; ++jb) {
        fsum[jb] += __shfl_xor(fsum[jb], off, 64);
        fmx[jb] = fmaxf(fmx[jb], __shfl_xor(fmx[jb], off, 64));
      }
    }
    if (quad == 0) {
      rowS[h * 128 + w * 32 + n15] = fsum[0] * (1.0f / 128.0f) + fmx[0];
      rowS[h * 128 + w * 32 + 16 + n15] = fsum[1] * (1.0f / 128.0f) + fmx[1];
    }

    __syncthreads();  // Ks[buf] reads done; Ks[nb] visible; rowS visible
  }

  // ---- fused tail: softmax over b + attn bmm; wave w handles heads 2w,2w+1
#pragma unroll
  for (int hh = 0; hh < 2; ++hh) {
    const int h = w * 2 + hh;
    const int i = batch * 8 + h;
    float f0 = rowS[h * 128 + lane], f1 = rowS[h * 128 + 64 + lane];
    float m = fmaxf(f0, f1);
#pragma unroll
    for (int off = 32; off >= 1; off >>= 1) m = fmaxf(m, __shfl_xor(m, off, 64));
    const float e0 = expf(f0 - m), e1 = expf(f1 - m);
    float s = e0 + e1;
#pragma unroll
    for (int off = 32; off >= 1; off >>= 1) s += __shfl_xor(s, off, 64);
    const float inv = 1.0f / s;
    rowS[h * 128 + lane] = e0 * inv;       // same wave produces & consumes:
    rowS[h * 128 + 64 + lane] = e1 * inv;  // no barrier needed
    const float* __restrict__ qp = qh + (size_t)i * 8192 + lane;
    float acc2 = 0.0f;
#pragma unroll 8
    for (int b = 0; b < 128; ++b)
      acc2 = fmaf(rowS[h * 128 + b], qp[b * 64], acc2);
    const size_t idx = ((size_t)a * 8 + batch) * 512 + h * 64 + lane;
    const unsigned short hi = bf16r(acc2);
    attn_h[idx] = hi;
    attn_l[idx] = bf16r(acc2 - bf16f(hi));
  }
}

// ---------------------------------------------------------------------------
// Kernel D v6: R9-verbatim (gload_lds single-barrier template).
// ---------------------------------------------------------------------------
__global__ __launch_bounds__(256)
void outmm_kernel(const unsigned short* __restrict__ Xah,
                  const unsigned short* __restrict__ Xal,
                  const unsigned short* __restrict__ Owh,
                  const unsigned short* __restrict__ Owl,
                  const float* __restrict__ bias,
                  float* __restrict__ out) {
  __shared__ __align__(16) unsigned short S[2][12288];
  const int n0 = blockIdx.x * 32;  // 0..480
  const int m0 = blockIdx.y * 64;  // 0..960
  const int tid = threadIdx.x;
  const int w = tid >> 6, lane = tid & 63;
  const int quad = lane >> 4, n15 = lane & 15;
  const int lrow = lane >> 3;
  const int colOff = ((lane & 7) ^ lrow) * 8;

  const unsigned short* gb[6];
  int lo[6];
#pragma unroll
  for (int j = 0; j < 6; ++j) {
    const int c = w * 6 + j;
    const unsigned short* gsrc;
    int off, grow;
    if (c < 8)       { gsrc = Xah; off = c * 512;               grow = m0 + c * 8; }
    else if (c < 16) { gsrc = Xal; off = 4096 + (c - 8) * 512;   grow = m0 + (c - 8) * 8; }
    else if (c < 20) { gsrc = Owh; off = 8192 + (c - 16) * 512;  grow = n0 + (c - 16) * 8; }
    else             { gsrc = Owl; off = 10240 + (c - 20) * 512; grow = n0 + (c - 20) * 8; }
    gb[j] = gsrc + (size_t)(grow + lrow) * 512 + colOff;
    lo[j] = off;
  }

  f32x4 acc[2];
#pragma unroll
  for (int nt = 0; nt < 2; ++nt) acc[nt] = (f32x4){0.f, 0.f, 0.f, 0.f};

#pragma unroll
  for (int j = 0; j < 6; ++j) gload16(gb[j], &S[0][lo[j]]);
  __syncthreads();

  const int rA = w * 16 + n15;
  const int swz = n15 & 7;
  int side = 0;
  for (int k0 = 0; k0 < 512; k0 += 64) {
    if (k0 + 64 < 512) {
      const int ns = side ^ 1;
#pragma unroll
      for (int j = 0; j < 6; ++j) gload16(gb[j] + k0 + 64, &S[ns][lo[j]]);
    }
#pragma unroll
    for (int kk = 0; kk < 2; ++kk) {
      const int gA0 = ((kk * 4 + quad) ^ swz) * 8;
      short8 ah = *(const short8*)&S[side][rA * 64 + gA0];
      short8 al = *(const short8*)&S[side][4096 + rA * 64 + gA0];
#pragma unroll
      for (int nt = 0; nt < 2; ++nt) {
        const int rB = nt * 16 + n15;
        short8 bh = *(const short8*)&S[side][8192 + rB * 64 + gA0];
        short8 bl = *(const short8*)&S[side][10240 + rB * 64 + gA0];
        acc[nt] = __builtin_amdgcn_mfma_f32_16x16x32_bf16(ah, bh, acc[nt], 0, 0, 0);
        acc[nt] = __builtin_amdgcn_mfma_f32_16x16x32_bf16(ah, bl, acc[nt], 0, 0, 0);
        acc[nt] = __builtin_amdgcn_mfma_f32_16x16x32_bf16(al, bh, acc[nt], 0, 0, 0);
      }
    }
    if (k0 + 64 < 512) {
      __syncthreads();
      side ^= 1;
    }
  }

#pragma unroll
  for (int nt = 0; nt < 2; ++nt) {
    const int j = n0 + nt * 16 + n15;
    const float bj = bias[j];
#pragma unroll
    for (int r = 0; r < 4; ++r) {
      const int row = m0 + w * 16 + quad * 4 + r;
      out[(size_t)row * 512 + j] = acc[nt][r] + bj;
    }
  }
}

extern "C" void kernel_launch(void* const* d_in, const int* in_sizes, int n_in,
                              void* d_out, int out_size, void* d_ws,
                              size_t ws_size, hipStream_t stream) {
  const float* query = (const float*)d_in[0];
  const float* key   = (const float*)d_in[1];
  const float* value = (const float*)d_in[2];
  const float* cbias = (const float*)d_in[3];
  const float* W     = (const float*)d_in[4];
  const float* pb    = (const float*)d_in[5];
  const float* out_w = (const float*)d_in[6];
  const float* out_b = (const float*)d_in[7];
  float* out = (float*)d_out;

  float* ws = (float*)d_ws;
  float* qh = ws;                                            // 524288 f
  float* kh = ws + 524288;                                   // 524288 f
  unsigned short* vh     = (unsigned short*)(ws + 1048576);  // 524288 us
  unsigned short* attn_h = (unsigned short*)(ws + 1310720);  // 524288 us
  unsigned short* attn_l = (unsigned short*)(ws + 1572864);  // 524288 us
  unsigned short* Xh     = (unsigned short*)(ws + 1835008);  // 1572864 us
  unsigned short* Xl     = (unsigned short*)(ws + 2621440);  // 1572864 us
  unsigned short* Wh     = (unsigned short*)(ws + 3407872);  // 786432 us
  unsigned short* Wl     = (unsigned short*)(ws + 3801088);  // 786432 us
  unsigned short* Owh    = (unsigned short*)(ws + 4194304);  // 262144 us
  unsigned short* Owl    = (unsigned short*)(ws + 4325376);  // 262144 us

  prep_kernel<<<2560, 256, 0, stream>>>(query, key, value, W, out_w,
                                        Xh, Xl, Wh, Wl, Owh, Owl);
  projmm_kernel<<<dim3(48, 16), 256, 0, stream>>>(Xh, Xl, Wh, Wl, pb,
                                                  qh, kh, vh);
  score_kernel<<<1024, 256, 0, stream>>>(qh, kh, vh, cbias, attn_h, attn_l);
  outmm_kernel<<<dim3(16, 16), 256, 0, stream>>>(attn_h, attn_l, Owh, Owl,
                                                 out_b, out);
}

// Round 12
// 181.385 us; speedup vs baseline: 1.5728x; 1.5728x over previous
//
#include <hip/hip_runtime.h>
#include <math.h>

#define SCALING 0.125f

typedef __attribute__((ext_vector_type(8))) short short8;
typedef __attribute__((ext_vector_type(4))) float f32x4;

// round-to-nearest-even fp32 -> bf16
static __device__ __forceinline__ unsigned short bf16r(float x) {
  unsigned int u = __float_as_uint(x);
  u += 0x7fffu + ((u >> 16) & 1u);
  return (unsigned short)(u >> 16);
}
static __device__ __forceinline__ float bf16f(unsigned short h) {
  return __uint_as_float(((unsigned int)h) << 16);
}
// pack two fp32 -> bf16x2 via v_perm_b32 merge
static __device__ __forceinline__ unsigned int pk_bf16(float lo, float hi) {
  unsigned int ua = __float_as_uint(lo);
  unsigned int ub = __float_as_uint(hi);
  ua += 0x7fffu + ((ua >> 16) & 1u);
  ub += 0x7fffu + ((ub >> 16) & 1u);
  return __builtin_amdgcn_perm(ub, ua, 0x07060302u);
}
// fp32x4 -> bf16 hi + residual lo
static __device__ __forceinline__ void split4(float4 x, ushort4& h, ushort4& l) {
  h.x = bf16r(x.x); l.x = bf16r(x.x - bf16f(h.x));
  h.y = bf16r(x.y); l.y = bf16r(x.y - bf16f(h.y));
  h.z = bf16r(x.z); l.z = bf16r(x.z - bf16f(h.z));
  h.w = bf16r(x.w); l.w = bf16r(x.w - bf16f(h.w));
}
union U4S8 { uint4 u; short8 s; };

// async global->LDS, 16B per lane (wave-uniform LDS base + lane*16; per-lane
// global address). Tracked by vmcnt; __syncthreads drains it (m97 semantics).
static __device__ __forceinline__ void gload16(const unsigned short* g,
                                               unsigned short* l) {
  __builtin_amdgcn_global_load_lds(
      (const __attribute__((address_space(1))) void*)(g),
      (__attribute__((address_space(3))) void*)(l), 16, 0, 0);
}

// ---------------------------------------------------------------------------
// Kernel P: one-shot hi/lo bf16 split of all loop-invariant GEMM operands.
// R3-verbatim.
// ---------------------------------------------------------------------------
__global__ __launch_bounds__(256)
void prep_kernel(const float* __restrict__ query,
                 const float* __restrict__ key,
                 const float* __restrict__ value,
                 const float* __restrict__ W,
                 const float* __restrict__ out_w,
                 unsigned short* __restrict__ Xh,
                 unsigned short* __restrict__ Xl,
                 unsigned short* __restrict__ Wh,
                 unsigned short* __restrict__ Wl,
                 unsigned short* __restrict__ Owh,
                 unsigned short* __restrict__ Owl) {
  const int t = blockIdx.x * 256 + threadIdx.x;  // 0..655359
  const int e = t * 4;
  const float* __restrict__ src;
  unsigned short *dh, *dl;
  if (e < 1572864) {               // query|key|value: 3 x 524288 floats
    const int g = e >> 19, j = e & 524287;
    src = (g == 0 ? query : g == 1 ? key : value) + j;
    dh = Xh + e; dl = Xl + e;
  } else if (e < 2359296) {        // W: 1536x512
    const int j = e - 1572864;
    src = W + j; dh = Wh + j; dl = Wl + j;
  } else {                         // out_w: 512x512
    const int j = e - 2359296;
    src = out_w + j; dh = Owh + j; dl = Owl + j;
  }
  const float4 v = *(const float4*)src;
  ushort4 hh, ll;
  split4(v, hh, ll);
  *(ushort4*)dh = hh;
  *(ushort4*)dl = ll;
}

// ---------------------------------------------------------------------------
// Kernel A v6: R9-verbatim (gload_lds direct staging, double buffer, one
// barrier per K-step, rule-#21 both-sides swizzle). Measured best.
// ---------------------------------------------------------------------------
__global__ __launch_bounds__(256)
void projmm_kernel(const unsigned short* __restrict__ Xh,
                   const unsigned short* __restrict__ Xl,
                   const unsigned short* __restrict__ Wh,
                   const unsigned short* __restrict__ Wl,
                   const float* __restrict__ bias,
                   float* __restrict__ qh, float* __restrict__ kh,
                   unsigned short* __restrict__ vh) {
  __shared__ __align__(16) unsigned short S[2][12288];
  const int n0 = blockIdx.x * 32;  // 0..1504
  const int g = n0 >> 9;           // 0=q,1=k,2=v (32-tiles never straddle 512)
  const unsigned short* __restrict__ Xgh = Xh + g * 524288;
  const unsigned short* __restrict__ Xgl = Xl + g * 524288;
  const int m0 = blockIdx.y * 64;
  const int tid = threadIdx.x;
  const int w = tid >> 6, lane = tid & 63;
  const int quad = lane >> 4, n15 = lane & 15;
  const int lrow = lane >> 3;                       // 0..7 (chunk-local row)
  const int colOff = ((lane & 7) ^ lrow) * 8;       // inverse-swz source col

  // per-wave 6 staging chunks: global base (sans k0) + LDS offset
  const unsigned short* gb[6];
  int lo[6];
#pragma unroll
  for (int j = 0; j < 6; ++j) {
    const int c = w * 6 + j;
    const unsigned short* gsrc;
    int off, grow;
    if (c < 8)       { gsrc = Xgh; off = c * 512;              grow = m0 + c * 8; }
    else if (c < 16) { gsrc = Xgl; off = 4096 + (c - 8) * 512;  grow = m0 + (c - 8) * 8; }
    else if (c < 20) { gsrc = Wh;  off = 8192 + (c - 16) * 512; grow = n0 + (c - 16) * 8; }
    else             { gsrc = Wl;  off = 10240 + (c - 20) * 512; grow = n0 + (c - 20) * 8; }
    gb[j] = gsrc + (size_t)(grow + lrow) * 512 + colOff;
    lo[j] = off;
  }

  f32x4 acc[2];
#pragma unroll
  for (int nt = 0; nt < 2; ++nt) acc[nt] = (f32x4){0.f, 0.f, 0.f, 0.f};

  // prologue: stage k-tile 0 into side 0
#pragma unroll
  for (int j = 0; j < 6; ++j) gload16(gb[j], &S[0][lo[j]]);
  __syncthreads();

  const int rA = w * 16 + n15;
  const int swz = n15 & 7;
  int side = 0;
  for (int k0 = 0; k0 < 512; k0 += 64) {
    if (k0 + 64 < 512) {
      const int ns = side ^ 1;
#pragma unroll
      for (int j = 0; j < 6; ++j) gload16(gb[j] + k0 + 64, &S[ns][lo[j]]);
    }
#pragma unroll
    for (int kk = 0; kk < 2; ++kk) {
      const int gA0 = ((kk * 4 + quad) ^ swz) * 8;
      short8 ah = *(const short8*)&S[side][rA * 64 + gA0];
      short8 al = *(const short8*)&S[side][4096 + rA * 64 + gA0];
#pragma unroll
      for (int nt = 0; nt < 2; ++nt) {
        const int rB = nt * 16 + n15;
        short8 bh = *(const short8*)&S[side][8192 + rB * 64 + gA0];
        short8 bl = *(const short8*)&S[side][10240 + rB * 64 + gA0];
        acc[nt] = __builtin_amdgcn_mfma_f32_16x16x32_bf16(ah, bh, acc[nt], 0, 0, 0);
        acc[nt] = __builtin_amdgcn_mfma_f32_16x16x32_bf16(ah, bl, acc[nt], 0, 0, 0);
        acc[nt] = __builtin_amdgcn_mfma_f32_16x16x32_bf16(al, bh, acc[nt], 0, 0, 0);
      }
    }
    if (k0 + 64 < 512) {
      __syncthreads();  // drains vmcnt (stage done) + all reads of 'side' done
      side ^= 1;
    }
  }

#pragma unroll
  for (int nt = 0; nt < 2; ++nt) {
    const int j = n0 + nt * 16 + n15;
    const int jj = j & 511;
    const int head = jj >> 6;
    const int hd = jj & 63;
    const float bj = bias[j];
#pragma unroll
    for (int r = 0; r < 4; ++r) {
      const int row = m0 + w * 16 + quad * 4 + r;
      const int t = row >> 3;
      const int batch = row & 7;
      const int i = batch * 8 + head;
      const int idx = ((i << 7) + t) * 64 + hd;
      const float val = acc[nt][r] + bj;
      if (g == 0)      qh[idx] = val * SCALING;
      else if (g == 1) kh[idx] = val;
      else             vh[idx] = bf16r(val);
    }
  }
}

// ---------------------------------------------------------------------------
// Kernel B v5 (R10-verbatim): Ks/Vs cooperative LDS staging (mandatory —
// R4/R5/R11 proved per-lane gathers lose 2-3x), NT bias preload, XCD batch
// swizzle, bias as MFMA C-init. Best-replicated score: 64.6-65.7 us.
// ---------------------------------------------------------------------------
__global__ __launch_bounds__(256, 2)
void score_kernel(const float* __restrict__ qh,
                  const float* __restrict__ kh,
                  const unsigned short* __restrict__ vh,
                  const float* __restrict__ cbias,
                  unsigned short* __restrict__ attn_h,
                  unsigned short* __restrict__ attn_l) {
  __shared__ __align__(16) unsigned short Ks[2][128 * 72];
  __shared__ __align__(16) unsigned short Vs[2][128 * 72];
  __shared__ float rowS[8 * 128];  // fused rows, then softmax weights

  const int d = blockIdx.x;
  const int ab = ((d & 7) << 7) | (d >> 3);  // batch = d&7 -> XCD-local batch
  const int batch = ab >> 7;
  const int a = ab & 127;
  const int tid = threadIdx.x;
  const int w = tid >> 6;
  const int lane = tid & 63;
  const int quad = lane >> 4;
  const int n15 = lane & 15;
  const int col8 = (tid & 7) * 8;

  // bias fragment preload (head-invariant coords; verified mapping) — NT loads
  const float* __restrict__ bp = cbias + (size_t)ab * 16384;
  f32x4 biasReg[8][2];
#pragma unroll
  for (int ic = 0; ic < 8; ++ic)
#pragma unroll
    for (int jb = 0; jb < 2; ++jb) {
      const int b = w * 32 + jb * 16 + n15;
      biasReg[ic][jb] = __builtin_nontemporal_load(
          (const f32x4*)&bp[b * 128 + ic * 16 + quad * 4]);
    }

  // ---- prologue: stage head 0 into buffer 0 ----
  {
    const int i = batch * 8;
    const float* __restrict__ kb = kh + (size_t)i * 8192;
    const uint4* __restrict__ vb4 = (const uint4*)(vh + (size_t)i * 8192);
    const float* __restrict__ qa = qh + ((size_t)i * 128 + a) * 64;
    f32x4 q0 = *(const f32x4*)&qa[col8];
    f32x4 q1 = *(const f32x4*)&qa[col8 + 4];
#pragma unroll
    for (int j = 0; j < 4; ++j) {
      const int gg = j * 256 + tid;
      const int row = gg >> 3;
      *(uint4*)&Vs[0][row * 72 + col8] = vb4[gg];
      f32x4 k0 = *(const f32x4*)&kb[8 * gg];
      f32x4 k1 = *(const f32x4*)&kb[8 * gg + 4];
      k0 *= q0;
      k1 *= q1;
      uint4 pk;
      pk.x = pk_bf16(k0[0], k0[1]); pk.y = pk_bf16(k0[2], k0[3]);
      pk.z = pk_bf16(k1[0], k1[1]); pk.w = pk_bf16(k1[2], k1[3]);
      *(uint4*)&Ks[0][row * 72 + col8] = pk;
    }
  }
  __syncthreads();

  for (int h = 0; h < 8; ++h) {
    const int buf = h & 1;
    const int i = batch * 8 + h;

    // ---- issue next head's global loads (in flight during MFMA)
    uint4 vreg[4];
    f32x4 kreg[4][2];
    f32x4 qn0, qn1;
    if (h < 7) {
      const int in = i + 1;
      const float* __restrict__ kb = kh + (size_t)in * 8192;
      const uint4* __restrict__ vb4 = (const uint4*)(vh + (size_t)in * 8192);
      const float* __restrict__ qa = qh + ((size_t)in * 128 + a) * 64;
      qn0 = *(const f32x4*)&qa[col8];
      qn1 = *(const f32x4*)&qa[col8 + 4];
#pragma unroll
      for (int j = 0; j < 4; ++j) {
        const int gg = j * 256 + tid;
        vreg[j] = vb4[gg];
        kreg[j][0] = *(const f32x4*)&kb[8 * gg];
        kreg[j][1] = *(const f32x4*)&kb[8 * gg + 4];
      }
    }

    // ---- B-fragments from Ks[buf]
    short8 bf[2][2];
#pragma unroll
    for (int jb = 0; jb < 2; ++jb)
#pragma unroll
      for (int kk = 0; kk < 2; ++kk)
        bf[jb][kk] = *(const short8*)&Ks[buf][(w * 32 + jb * 16 + n15) * 72 +
                                             kk * 32 + quad * 8];

    // ---- MFMA: S^T[c,b]; bias as C-init (R1-verified)
    f32x4 acc[8][2];
#pragma unroll
    for (int ic = 0; ic < 8; ++ic) {
      short8 a0 = *(const short8*)&Vs[buf][(ic * 16 + n15) * 72 + quad * 8];
      short8 a1 = *(const short8*)&Vs[buf][(ic * 16 + n15) * 72 + 32 + quad * 8];
      acc[ic][0] = __builtin_amdgcn_mfma_f32_16x16x32_bf16(a0, bf[0][0], biasReg[ic][0], 0, 0, 0);
      acc[ic][0] = __builtin_amdgcn_mfma_f32_16x16x32_bf16(a1, bf[0][1], acc[ic][0], 0, 0, 0);
      acc[ic][1] = __builtin_amdgcn_mfma_f32_16x16x32_bf16(a0, bf[1][0], biasReg[ic][1], 0, 0, 0);
      acc[ic][1] = __builtin_amdgcn_mfma_f32_16x16x32_bf16(a1, bf[1][1], acc[ic][1], 0, 0, 0);
    }

    // ---- pack + store next head's staging into the other buffer
    if (h < 7) {
      const int nb = buf ^ 1;
#pragma unroll
      for (int j = 0; j < 4; ++j) {
        const int gg = j * 256 + tid;
        const int row = gg >> 3;
        *(uint4*)&Vs[nb][row * 72 + col8] = vreg[j];
        kreg[j][0] *= qn0;
        kreg[j][1] *= qn1;
        uint4 pk;
        pk.x = pk_bf16(kreg[j][0][0], kreg[j][0][1]);
        pk.y = pk_bf16(kreg[j][0][2], kreg[j][0][3]);
        pk.z = pk_bf16(kreg[j][1][0], kreg[j][1][1]);
        pk.w = pk_bf16(kreg[j][1][2], kreg[j][1][3]);
        *(uint4*)&Ks[nb][row * 72 + col8] = pk;
      }
    }

    // ---- epilogue: mean/max over c (bias already in acc) -> rowS (LDS)
    float fsum[2] = {0.f, 0.f};
    float fmx[2] = {-INFINITY, -INFINITY};
#pragma unroll
    for (int ic = 0; ic < 8; ++ic)
#pragma unroll
      for (int jb = 0; jb < 2; ++jb) {
        const float v0 = acc[ic][jb][0];
        const float v1 = acc[ic][jb][1];
        const float v2 = acc[ic][jb][2];
        const float v3 = acc[ic][jb][3];
        fsum[jb] += (v0 + v1) + (v2 + v3);
        fmx[jb] = fmaxf(fmx[jb], fmaxf(fmaxf(v0, v1), fmaxf(v2, v3)));
      }
#pragma unroll
    for (int off = 16; off <= 32; off <<= 1) {
#pragma unroll
      for (int jb = 0; jb < 2; ++jb) {
        fsum[jb] += __shfl_xor(fsum[jb], off, 64);
        fmx[jb] = fmaxf(fmx[jb], __shfl_xor(fmx[jb], off, 64));
      }
    }
    if (quad == 0) {
      rowS[h * 128 + w * 32 + n15] = fsum[0] * (1.0f / 128.0f) + fmx[0];
      rowS[h * 128 + w * 32 + 16 + n15] = fsum[1] * (1.0f / 128.0f) + fmx[1];
    }

    __syncthreads();  // h's reads done; h's stores visible; rowS visible
  }

  // ---- fused tail: softmax over b + attn bmm; wave w handles heads 2w,2w+1
#pragma unroll
  for (int hh = 0; hh < 2; ++hh) {
    const int h = w * 2 + hh;
    const int i = batch * 8 + h;
    float f0 = rowS[h * 128 + lane], f1 = rowS[h * 128 + 64 + lane];
    float m = fmaxf(f0, f1);
#pragma unroll
    for (int off = 32; off >= 1; off >>= 1) m = fmaxf(m, __shfl_xor(m, off, 64));
    const float e0 = expf(f0 - m), e1 = expf(f1 - m);
    float s = e0 + e1;
#pragma unroll
    for (int off = 32; off >= 1; off >>= 1) s += __shfl_xor(s, off, 64);
    const float inv = 1.0f / s;
    rowS[h * 128 + lane] = e0 * inv;       // same wave produces & consumes:
    rowS[h * 128 + 64 + lane] = e1 * inv;  // no barrier needed
    const float* __restrict__ qp = qh + (size_t)i * 8192 + lane;
    float acc2 = 0.0f;
#pragma unroll 8
    for (int b = 0; b < 128; ++b)
      acc2 = fmaf(rowS[h * 128 + b], qp[b * 64], acc2);
    const size_t idx = ((size_t)a * 8 + batch) * 512 + h * 64 + lane;
    const unsigned short hi = bf16r(acc2);
    attn_h[idx] = hi;
    attn_l[idx] = bf16r(acc2 - bf16f(hi));
  }
}

// ---------------------------------------------------------------------------
// Kernel D v6: R9-verbatim (gload_lds single-barrier template).
// ---------------------------------------------------------------------------
__global__ __launch_bounds__(256)
void outmm_kernel(const unsigned short* __restrict__ Xah,
                  const unsigned short* __restrict__ Xal,
                  const unsigned short* __restrict__ Owh,
                  const unsigned short* __restrict__ Owl,
                  const float* __restrict__ bias,
                  float* __restrict__ out) {
  __shared__ __align__(16) unsigned short S[2][12288];
  const int n0 = blockIdx.x * 32;  // 0..480
  const int m0 = blockIdx.y * 64;  // 0..960
  const int tid = threadIdx.x;
  const int w = tid >> 6, lane = tid & 63;
  const int quad = lane >> 4, n15 = lane & 15;
  const int lrow = lane >> 3;
  const int colOff = ((lane & 7) ^ lrow) * 8;

  const unsigned short* gb[6];
  int lo[6];
#pragma unroll
  for (int j = 0; j < 6; ++j) {
    const int c = w * 6 + j;
    const unsigned short* gsrc;
    int off, grow;
    if (c < 8)       { gsrc = Xah; off = c * 512;               grow = m0 + c * 8; }
    else if (c < 16) { gsrc = Xal; off = 4096 + (c - 8) * 512;   grow = m0 + (c - 8) * 8; }
    else if (c < 20) { gsrc = Owh; off = 8192 + (c - 16) * 512;  grow = n0 + (c - 16) * 8; }
    else             { gsrc = Owl; off = 10240 + (c - 20) * 512; grow = n0 + (c - 20) * 8; }
    gb[j] = gsrc + (size_t)(grow + lrow) * 512 + colOff;
    lo[j] = off;
  }

  f32x4 acc[2];
#pragma unroll
  for (int nt = 0; nt < 2; ++nt) acc[nt] = (f32x4){0.f, 0.f, 0.f, 0.f};

#pragma unroll
  for (int j = 0; j < 6; ++j) gload16(gb[j], &S[0][lo[j]]);
  __syncthreads();

  const int rA = w * 16 + n15;
  const int swz = n15 & 7;
  int side = 0;
  for (int k0 = 0; k0 < 512; k0 += 64) {
    if (k0 + 64 < 512) {
      const int ns = side ^ 1;
#pragma unroll
      for (int j = 0; j < 6; ++j) gload16(gb[j] + k0 + 64, &S[ns][lo[j]]);
    }
#pragma unroll
    for (int kk = 0; kk < 2; ++kk) {
      const int gA0 = ((kk * 4 + quad) ^ swz) * 8;
      short8 ah = *(const short8*)&S[side][rA * 64 + gA0];
      short8 al = *(const short8*)&S[side][4096 + rA * 64 + gA0];
#pragma unroll
      for (int nt = 0; nt < 2; ++nt) {
        const int rB = nt * 16 + n15;
        short8 bh = *(const short8*)&S[side][8192 + rB * 64 + gA0];
        short8 bl = *(const short8*)&S[side][10240 + rB * 64 + gA0];
        acc[nt] = __builtin_amdgcn_mfma_f32_16x16x32_bf16(ah, bh, acc[nt], 0, 0, 0);
        acc[nt] = __builtin_amdgcn_mfma_f32_16x16x32_bf16(ah, bl, acc[nt], 0, 0, 0);
        acc[nt] = __builtin_amdgcn_mfma_f32_16x16x32_bf16(al, bh, acc[nt], 0, 0, 0);
      }
    }
    if (k0 + 64 < 512) {
      __syncthreads();
      side ^= 1;
    }
  }

#pragma unroll
  for (int nt = 0; nt < 2; ++nt) {
    const int j = n0 + nt * 16 + n15;
    const float bj = bias[j];
#pragma unroll
    for (int r = 0; r < 4; ++r) {
      const int row = m0 + w * 16 + quad * 4 + r;
      out[(size_t)row * 512 + j] = acc[nt][r] + bj;
    }
  }
}

extern "C" void kernel_launch(void* const* d_in, const int* in_sizes, int n_in,
                              void* d_out, int out_size, void* d_ws,
                              size_t ws_size, hipStream_t stream) {
  const float* query = (const float*)d_in[0];
  const float* key   = (const float*)d_in[1];
  const float* value = (const float*)d_in[2];
  const float* cbias = (const float*)d_in[3];
  const float* W     = (const float*)d_in[4];
  const float* pb    = (const float*)d_in[5];
  const float* out_w = (const float*)d_in[6];
  const float* out_b = (const float*)d_in[7];
  float* out = (float*)d_out;

  float* ws = (float*)d_ws;
  float* qh = ws;                                            // 524288 f
  float* kh = ws + 524288;                                   // 524288 f
  unsigned short* vh     = (unsigned short*)(ws + 1048576);  // 524288 us
  unsigned short* attn_h = (unsigned short*)(ws + 1310720);  // 524288 us
  unsigned short* attn_l = (unsigned short*)(ws + 1572864);  // 524288 us
  unsigned short* Xh     = (unsigned short*)(ws + 1835008);  // 1572864 us
  unsigned short* Xl     = (unsigned short*)(ws + 2621440);  // 1572864 us
  unsigned short* Wh     = (unsigned short*)(ws + 3407872);  // 786432 us
  unsigned short* Wl     = (unsigned short*)(ws + 3801088);  // 786432 us
  unsigned short* Owh    = (unsigned short*)(ws + 4194304);  // 262144 us
  unsigned short* Owl    = (unsigned short*)(ws + 4325376);  // 262144 us

  prep_kernel<<<2560, 256, 0, stream>>>(query, key, value, W, out_w,
                                        Xh, Xl, Wh, Wl, Owh, Owl);
  projmm_kernel<<<dim3(48, 16), 256, 0, stream>>>(Xh, Xl, Wh, Wl, pb,
                                                  qh, kh, vh);
  score_kernel<<<1024, 256, 0, stream>>>(qh, kh, vh, cbias, attn_h, attn_l);
  outmm_kernel<<<dim3(16, 16), 256, 0, stream>>>(attn_h, attn_l, Owh, Owl,
                                                 out_b, out);
}

// Round 13
// 179.138 us; speedup vs baseline: 1.5925x; 1.0125x over previous
//
#include <hip/hip_runtime.h>
#include <math.h>

#define SCALING 0.125f

typedef __attribute__((ext_vector_type(8))) short short8;
typedef __attribute__((ext_vector_type(4))) float f32x4;

// round-to-nearest-even fp32 -> bf16
static __device__ __forceinline__ unsigned short bf16r(float x) {
  unsigned int u = __float_as_uint(x);
  u += 0x7fffu + ((u >> 16) & 1u);
  return (unsigned short)(u >> 16);
}
static __device__ __forceinline__ float bf16f(unsigned short h) {
  return __uint_as_float(((unsigned int)h) << 16);
}
// pack two fp32 -> bf16x2 via v_perm_b32 merge
static __device__ __forceinline__ unsigned int pk_bf16(float lo, float hi) {
  unsigned int ua = __float_as_uint(lo);
  unsigned int ub = __float_as_uint(hi);
  ua += 0x7fffu + ((ua >> 16) & 1u);
  ub += 0x7fffu + ((ub >> 16) & 1u);
  return __builtin_amdgcn_perm(ub, ua, 0x07060302u);
}
// fp32x4 -> bf16 hi + residual lo
static __device__ __forceinline__ void split4(float4 x, ushort4& h, ushort4& l) {
  h.x = bf16r(x.x); l.x = bf16r(x.x - bf16f(h.x));
  h.y = bf16r(x.y); l.y = bf16r(x.y - bf16f(h.y));
  h.z = bf16r(x.z); l.z = bf16r(x.z - bf16f(h.z));
  h.w = bf16r(x.w); l.w = bf16r(x.w - bf16f(h.w));
}
union U4S8 { uint4 u; short8 s; };

// async global->LDS, 16B per lane (wave-uniform LDS base + lane*16; per-lane
// global address). Tracked by vmcnt; __syncthreads drains it (m97 semantics).
static __device__ __forceinline__ void gload16(const unsigned short* g,
                                               unsigned short* l) {
  __builtin_amdgcn_global_load_lds(
      (const __attribute__((address_space(1))) void*)(g),
      (__attribute__((address_space(3))) void*)(l), 16, 0, 0);
}

// ---------------------------------------------------------------------------
// Kernel P: one-shot hi/lo bf16 split of all loop-invariant GEMM operands.
// R3-verbatim.
// ---------------------------------------------------------------------------
__global__ __launch_bounds__(256)
void prep_kernel(const float* __restrict__ query,
                 const float* __restrict__ key,
                 const float* __restrict__ value,
                 const float* __restrict__ W,
                 const float* __restrict__ out_w,
                 unsigned short* __restrict__ Xh,
                 unsigned short* __restrict__ Xl,
                 unsigned short* __restrict__ Wh,
                 unsigned short* __restrict__ Wl,
                 unsigned short* __restrict__ Owh,
                 unsigned short* __restrict__ Owl) {
  const int t = blockIdx.x * 256 + threadIdx.x;  // 0..655359
  const int e = t * 4;
  const float* __restrict__ src;
  unsigned short *dh, *dl;
  if (e < 1572864) {               // query|key|value: 3 x 524288 floats
    const int g = e >> 19, j = e & 524287;
    src = (g == 0 ? query : g == 1 ? key : value) + j;
    dh = Xh + e; dl = Xl + e;
  } else if (e < 2359296) {        // W: 1536x512
    const int j = e - 1572864;
    src = W + j; dh = Wh + j; dl = Wl + j;
  } else {                         // out_w: 512x512
    const int j = e - 2359296;
    src = out_w + j; dh = Owh + j; dl = Owl + j;
  }
  const float4 v = *(const float4*)src;
  ushort4 hh, ll;
  split4(v, hh, ll);
  *(ushort4*)dh = hh;
  *(ushort4*)dl = ll;
}

// ---------------------------------------------------------------------------
// Kernel A v6: R9-verbatim (gload_lds direct staging, double buffer, one
// barrier per K-step, rule-#21 both-sides swizzle). Measured best.
// ---------------------------------------------------------------------------
__global__ __launch_bounds__(256)
void projmm_kernel(const unsigned short* __restrict__ Xh,
                   const unsigned short* __restrict__ Xl,
                   const unsigned short* __restrict__ Wh,
                   const unsigned short* __restrict__ Wl,
                   const float* __restrict__ bias,
                   float* __restrict__ qh, float* __restrict__ kh,
                   unsigned short* __restrict__ vh) {
  __shared__ __align__(16) unsigned short S[2][12288];
  const int n0 = blockIdx.x * 32;  // 0..1504
  const int g = n0 >> 9;           // 0=q,1=k,2=v (32-tiles never straddle 512)
  const unsigned short* __restrict__ Xgh = Xh + g * 524288;
  const unsigned short* __restrict__ Xgl = Xl + g * 524288;
  const int m0 = blockIdx.y * 64;
  const int tid = threadIdx.x;
  const int w = tid >> 6, lane = tid & 63;
  const int quad = lane >> 4, n15 = lane & 15;
  const int lrow = lane >> 3;                       // 0..7 (chunk-local row)
  const int colOff = ((lane & 7) ^ lrow) * 8;       // inverse-swz source col

  // per-wave 6 staging chunks: global base (sans k0) + LDS offset
  const unsigned short* gb[6];
  int lo[6];
#pragma unroll
  for (int j = 0; j < 6; ++j) {
    const int c = w * 6 + j;
    const unsigned short* gsrc;
    int off, grow;
    if (c < 8)       { gsrc = Xgh; off = c * 512;              grow = m0 + c * 8; }
    else if (c < 16) { gsrc = Xgl; off = 4096 + (c - 8) * 512;  grow = m0 + (c - 8) * 8; }
    else if (c < 20) { gsrc = Wh;  off = 8192 + (c - 16) * 512; grow = n0 + (c - 16) * 8; }
    else             { gsrc = Wl;  off = 10240 + (c - 20) * 512; grow = n0 + (c - 20) * 8; }
    gb[j] = gsrc + (size_t)(grow + lrow) * 512 + colOff;
    lo[j] = off;
  }

  f32x4 acc[2];
#pragma unroll
  for (int nt = 0; nt < 2; ++nt) acc[nt] = (f32x4){0.f, 0.f, 0.f, 0.f};

  // prologue: stage k-tile 0 into side 0
#pragma unroll
  for (int j = 0; j < 6; ++j) gload16(gb[j], &S[0][lo[j]]);
  __syncthreads();

  const int rA = w * 16 + n15;
  const int swz = n15 & 7;
  int side = 0;
  for (int k0 = 0; k0 < 512; k0 += 64) {
    if (k0 + 64 < 512) {
      const int ns = side ^ 1;
#pragma unroll
      for (int j = 0; j < 6; ++j) gload16(gb[j] + k0 + 64, &S[ns][lo[j]]);
    }
#pragma unroll
    for (int kk = 0; kk < 2; ++kk) {
      const int gA0 = ((kk * 4 + quad) ^ swz) * 8;
      short8 ah = *(const short8*)&S[side][rA * 64 + gA0];
      short8 al = *(const short8*)&S[side][4096 + rA * 64 + gA0];
#pragma unroll
      for (int nt = 0; nt < 2; ++nt) {
        const int rB = nt * 16 + n15;
        short8 bh = *(const short8*)&S[side][8192 + rB * 64 + gA0];
        short8 bl = *(const short8*)&S[side][10240 + rB * 64 + gA0];
        acc[nt] = __builtin_amdgcn_mfma_f32_16x16x32_bf16(ah, bh, acc[nt], 0, 0, 0);
        acc[nt] = __builtin_amdgcn_mfma_f32_16x16x32_bf16(ah, bl, acc[nt], 0, 0, 0);
        acc[nt] = __builtin_amdgcn_mfma_f32_16x16x32_bf16(al, bh, acc[nt], 0, 0, 0);
      }
    }
    if (k0 + 64 < 512) {
      __syncthreads();  // drains vmcnt (stage done) + all reads of 'side' done
      side ^= 1;
    }
  }

#pragma unroll
  for (int nt = 0; nt < 2; ++nt) {
    const int j = n0 + nt * 16 + n15;
    const int jj = j & 511;
    const int head = jj >> 6;
    const int hd = jj & 63;
    const float bj = bias[j];
#pragma unroll
    for (int r = 0; r < 4; ++r) {
      const int row = m0 + w * 16 + quad * 4 + r;
      const int t = row >> 3;
      const int batch = row & 7;
      const int i = batch * 8 + head;
      const int idx = ((i << 7) + t) * 64 + hd;
      const float val = acc[nt][r] + bj;
      if (g == 0)      qh[idx] = val * SCALING;
      else if (g == 1) kh[idx] = val;
      else             vh[idx] = bf16r(val);
    }
  }
}

// ---------------------------------------------------------------------------
// Kernel B v7: R12 (Ks/Vs cooperative staging, NT bias, XCD swizzle, bias
// C-init) with ONE change: the fused-tail bmm gets 4-way partial
// accumulators + 4-wide body (G7 ILP). Breaks the 128-long serial fmaf
// chain 4x and lets ~16 independent q-loads pipeline (was ~8). fp32 sum
// reassociation only; output error stays bf16-quantization-dominated.
// ---------------------------------------------------------------------------
__global__ __launch_bounds__(256, 2)
void score_kernel(const float* __restrict__ qh,
                  const float* __restrict__ kh,
                  const unsigned short* __restrict__ vh,
                  const float* __restrict__ cbias,
                  unsigned short* __restrict__ attn_h,
                  unsigned short* __restrict__ attn_l) {
  __shared__ __align__(16) unsigned short Ks[2][128 * 72];
  __shared__ __align__(16) unsigned short Vs[2][128 * 72];
  __shared__ float rowS[8 * 128];  // fused rows, then softmax weights

  const int d = blockIdx.x;
  const int ab = ((d & 7) << 7) | (d >> 3);  // batch = d&7 -> XCD-local batch
  const int batch = ab >> 7;
  const int a = ab & 127;
  const int tid = threadIdx.x;
  const int w = tid >> 6;
  const int lane = tid & 63;
  const int quad = lane >> 4;
  const int n15 = lane & 15;
  const int col8 = (tid & 7) * 8;

  // bias fragment preload (head-invariant coords; verified mapping) — NT loads
  const float* __restrict__ bp = cbias + (size_t)ab * 16384;
  f32x4 biasReg[8][2];
#pragma unroll
  for (int ic = 0; ic < 8; ++ic)
#pragma unroll
    for (int jb = 0; jb < 2; ++jb) {
      const int b = w * 32 + jb * 16 + n15;
      biasReg[ic][jb] = __builtin_nontemporal_load(
          (const f32x4*)&bp[b * 128 + ic * 16 + quad * 4]);
    }

  // ---- prologue: stage head 0 into buffer 0 ----
  {
    const int i = batch * 8;
    const float* __restrict__ kb = kh + (size_t)i * 8192;
    const uint4* __restrict__ vb4 = (const uint4*)(vh + (size_t)i * 8192);
    const float* __restrict__ qa = qh + ((size_t)i * 128 + a) * 64;
    f32x4 q0 = *(const f32x4*)&qa[col8];
    f32x4 q1 = *(const f32x4*)&qa[col8 + 4];
#pragma unroll
    for (int j = 0; j < 4; ++j) {
      const int gg = j * 256 + tid;
      const int row = gg >> 3;
      *(uint4*)&Vs[0][row * 72 + col8] = vb4[gg];
      f32x4 k0 = *(const f32x4*)&kb[8 * gg];
      f32x4 k1 = *(const f32x4*)&kb[8 * gg + 4];
      k0 *= q0;
      k1 *= q1;
      uint4 pk;
      pk.x = pk_bf16(k0[0], k0[1]); pk.y = pk_bf16(k0[2], k0[3]);
      pk.z = pk_bf16(k1[0], k1[1]); pk.w = pk_bf16(k1[2], k1[3]);
      *(uint4*)&Ks[0][row * 72 + col8] = pk;
    }
  }
  __syncthreads();

  for (int h = 0; h < 8; ++h) {
    const int buf = h & 1;
    const int i = batch * 8 + h;

    // ---- issue next head's global loads (in flight during MFMA)
    uint4 vreg[4];
    f32x4 kreg[4][2];
    f32x4 qn0, qn1;
    if (h < 7) {
      const int in = i + 1;
      const float* __restrict__ kb = kh + (size_t)in * 8192;
      const uint4* __restrict__ vb4 = (const uint4*)(vh + (size_t)in * 8192);
      const float* __restrict__ qa = qh + ((size_t)in * 128 + a) * 64;
      qn0 = *(const f32x4*)&qa[col8];
      qn1 = *(const f32x4*)&qa[col8 + 4];
#pragma unroll
      for (int j = 0; j < 4; ++j) {
        const int gg = j * 256 + tid;
        vreg[j] = vb4[gg];
        kreg[j][0] = *(const f32x4*)&kb[8 * gg];
        kreg[j][1] = *(const f32x4*)&kb[8 * gg + 4];
      }
    }

    // ---- B-fragments from Ks[buf]
    short8 bf[2][2];
#pragma unroll
    for (int jb = 0; jb < 2; ++jb)
#pragma unroll
      for (int kk = 0; kk < 2; ++kk)
        bf[jb][kk] = *(const short8*)&Ks[buf][(w * 32 + jb * 16 + n15) * 72 +
                                             kk * 32 + quad * 8];

    // ---- MFMA: S^T[c,b]; bias as C-init (R1-verified)
    f32x4 acc[8][2];
#pragma unroll
    for (int ic = 0; ic < 8; ++ic) {
      short8 a0 = *(const short8*)&Vs[buf][(ic * 16 + n15) * 72 + quad * 8];
      short8 a1 = *(const short8*)&Vs[buf][(ic * 16 + n15) * 72 + 32 + quad * 8];
      acc[ic][0] = __builtin_amdgcn_mfma_f32_16x16x32_bf16(a0, bf[0][0], biasReg[ic][0], 0, 0, 0);
      acc[ic][0] = __builtin_amdgcn_mfma_f32_16x16x32_bf16(a1, bf[0][1], acc[ic][0], 0, 0, 0);
      acc[ic][1] = __builtin_amdgcn_mfma_f32_16x16x32_bf16(a0, bf[1][0], biasReg[ic][1], 0, 0, 0);
      acc[ic][1] = __builtin_amdgcn_mfma_f32_16x16x32_bf16(a1, bf[1][1], acc[ic][1], 0, 0, 0);
    }

    // ---- pack + store next head's staging into the other buffer
    if (h < 7) {
      const int nb = buf ^ 1;
#pragma unroll
      for (int j = 0; j < 4; ++j) {
        const int gg = j * 256 + tid;
        const int row = gg >> 3;
        *(uint4*)&Vs[nb][row * 72 + col8] = vreg[j];
        kreg[j][0] *= qn0;
        kreg[j][1] *= qn1;
        uint4 pk;
        pk.x = pk_bf16(kreg[j][0][0], kreg[j][0][1]);
        pk.y = pk_bf16(kreg[j][0][2], kreg[j][0][3]);
        pk.z = pk_bf16(kreg[j][1][0], kreg[j][1][1]);
        pk.w = pk_bf16(kreg[j][1][2], kreg[j][1][3]);
        *(uint4*)&Ks[nb][row * 72 + col8] = pk;
      }
    }

    // ---- epilogue: mean/max over c (bias already in acc) -> rowS (LDS)
    float fsum[2] = {0.f, 0.f};
    float fmx[2] = {-INFINITY, -INFINITY};
#pragma unroll
    for (int ic = 0; ic < 8; ++ic)
#pragma unroll
      for (int jb = 0; jb < 2; ++jb) {
        const float v0 = acc[ic][jb][0];
        const float v1 = acc[ic][jb][1];
        const float v2 = acc[ic][jb][2];
        const float v3 = acc[ic][jb][3];
        fsum[jb] += (v0 + v1) + (v2 + v3);
        fmx[jb] = fmaxf(fmx[jb], fmaxf(fmaxf(v0, v1), fmaxf(v2, v3)));
      }
#pragma unroll
    for (int off = 16; off <= 32; off <<= 1) {
#pragma unroll
      for (int jb = 0; jb < 2; ++jb) {
        fsum[jb] += __shfl_xor(fsum[jb], off, 64);
        fmx[jb] = fmaxf(fmx[jb], __shfl_xor(fmx[jb], off, 64));
      }
    }
    if (quad == 0) {
      rowS[h * 128 + w * 32 + n15] = fsum[0] * (1.0f / 128.0f) + fmx[0];
      rowS[h * 128 + w * 32 + 16 + n15] = fsum[1] * (1.0f / 128.0f) + fmx[1];
    }

    __syncthreads();  // h's reads done; h's stores visible; rowS visible
  }

  // ---- fused tail: softmax over b + attn bmm; wave w handles heads 2w,2w+1
#pragma unroll
  for (int hh = 0; hh < 2; ++hh) {
    const int h = w * 2 + hh;
    const int i = batch * 8 + h;
    float f0 = rowS[h * 128 + lane], f1 = rowS[h * 128 + 64 + lane];
    float m = fmaxf(f0, f1);
#pragma unroll
    for (int off = 32; off >= 1; off >>= 1) m = fmaxf(m, __shfl_xor(m, off, 64));
    const float e0 = expf(f0 - m), e1 = expf(f1 - m);
    float s = e0 + e1;
#pragma unroll
    for (int off = 32; off >= 1; off >>= 1) s += __shfl_xor(s, off, 64);
    const float inv = 1.0f / s;
    rowS[h * 128 + lane] = e0 * inv;       // same wave produces & consumes:
    rowS[h * 128 + 64 + lane] = e1 * inv;  // no barrier needed
    const float* __restrict__ qp = qh + (size_t)i * 8192 + lane;
    // 4-way partial accumulators: serial fmaf chain 128 -> 32; ~16 q-loads
    // in flight (unroll 4 of the 4-wide body).
    float p0 = 0.f, p1 = 0.f, p2 = 0.f, p3 = 0.f;
#pragma unroll 4
    for (int b = 0; b < 128; b += 4) {
      p0 = fmaf(rowS[h * 128 + b],     qp[b * 64],       p0);
      p1 = fmaf(rowS[h * 128 + b + 1], qp[(b + 1) * 64], p1);
      p2 = fmaf(rowS[h * 128 + b + 2], qp[(b + 2) * 64], p2);
      p3 = fmaf(rowS[h * 128 + b + 3], qp[(b + 3) * 64], p3);
    }
    const float acc2 = (p0 + p1) + (p2 + p3);
    const size_t idx = ((size_t)a * 8 + batch) * 512 + h * 64 + lane;
    const unsigned short hi = bf16r(acc2);
    attn_h[idx] = hi;
    attn_l[idx] = bf16r(acc2 - bf16f(hi));
  }
}

// ---------------------------------------------------------------------------
// Kernel D v6: R9-verbatim (gload_lds single-barrier template).
// ---------------------------------------------------------------------------
__global__ __launch_bounds__(256)
void outmm_kernel(const unsigned short* __restrict__ Xah,
                  const unsigned short* __restrict__ Xal,
                  const unsigned short* __restrict__ Owh,
                  const unsigned short* __restrict__ Owl,
                  const float* __restrict__ bias,
                  float* __restrict__ out) {
  __shared__ __align__(16) unsigned short S[2][12288];
  const int n0 = blockIdx.x * 32;  // 0..480
  const int m0 = blockIdx.y * 64;  // 0..960
  const int tid = threadIdx.x;
  const int w = tid >> 6, lane = tid & 63;
  const int quad = lane >> 4, n15 = lane & 15;
  const int lrow = lane >> 3;
  const int colOff = ((lane & 7) ^ lrow) * 8;

  const unsigned short* gb[6];
  int lo[6];
#pragma unroll
  for (int j = 0; j < 6; ++j) {
    const int c = w * 6 + j;
    const unsigned short* gsrc;
    int off, grow;
    if (c < 8)       { gsrc = Xah; off = c * 512;               grow = m0 + c * 8; }
    else if (c < 16) { gsrc = Xal; off = 4096 + (c - 8) * 512;   grow = m0 + (c - 8) * 8; }
    else if (c < 20) { gsrc = Owh; off = 8192 + (c - 16) * 512;  grow = n0 + (c - 16) * 8; }
    else             { gsrc = Owl; off = 10240 + (c - 20) * 512; grow = n0 + (c - 20) * 8; }
    gb[j] = gsrc + (size_t)(grow + lrow) * 512 + colOff;
    lo[j] = off;
  }

  f32x4 acc[2];
#pragma unroll
  for (int nt = 0; nt < 2; ++nt) acc[nt] = (f32x4){0.f, 0.f, 0.f, 0.f};

#pragma unroll
  for (int j = 0; j < 6; ++j) gload16(gb[j], &S[0][lo[j]]);
  __syncthreads();

  const int rA = w * 16 + n15;
  const int swz = n15 & 7;
  int side = 0;
  for (int k0 = 0; k0 < 512; k0 += 64) {
    if (k0 + 64 < 512) {
      const int ns = side ^ 1;
#pragma unroll
      for (int j = 0; j < 6; ++j) gload16(gb[j] + k0 + 64, &S[ns][lo[j]]);
    }
#pragma unroll
    for (int kk = 0; kk < 2; ++kk) {
      const int gA0 = ((kk * 4 + quad) ^ swz) * 8;
      short8 ah = *(const short8*)&S[side][rA * 64 + gA0];
      short8 al = *(const short8*)&S[side][4096 + rA * 64 + gA0];
#pragma unroll
      for (int nt = 0; nt < 2; ++nt) {
        const int rB = nt * 16 + n15;
        short8 bh = *(const short8*)&S[side][8192 + rB * 64 + gA0];
        short8 bl = *(const short8*)&S[side][10240 + rB * 64 + gA0];
        acc[nt] = __builtin_amdgcn_mfma_f32_16x16x32_bf16(ah, bh, acc[nt], 0, 0, 0);
        acc[nt] = __builtin_amdgcn_mfma_f32_16x16x32_bf16(ah, bl, acc[nt], 0, 0, 0);
        acc[nt] = __builtin_amdgcn_mfma_f32_16x16x32_bf16(al, bh, acc[nt], 0, 0, 0);
      }
    }
    if (k0 + 64 < 512) {
      __syncthreads();
      side ^= 1;
    }
  }

#pragma unroll
  for (int nt = 0; nt < 2; ++nt) {
    const int j = n0 + nt * 16 + n15;
    const float bj = bias[j];
#pragma unroll
    for (int r = 0; r < 4; ++r) {
      const int row = m0 + w * 16 + quad * 4 + r;
      out[(size_t)row * 512 + j] = acc[nt][r] + bj;
    }
  }
}

extern "C" void kernel_launch(void* const* d_in, const int* in_sizes, int n_in,
                              void* d_out, int out_size, void* d_ws,
                              size_t ws_size, hipStream_t stream) {
  const float* query = (const float*)d_in[0];
  const float* key   = (const float*)d_in[1];
  const float* value = (const float*)d_in[2];
  const float* cbias = (const float*)d_in[3];
  const float* W     = (const float*)d_in[4];
  const float* pb    = (const float*)d_in[5];
  const float* out_w = (const float*)d_in[6];
  const float* out_b = (const float*)d_in[7];
  float* out = (float*)d_out;

  float* ws = (float*)d_ws;
  float* qh = ws;                                            // 524288 f
  float* kh = ws + 524288;                                   // 524288 f
  unsigned short* vh     = (unsigned short*)(ws + 1048576);  // 524288 us
  unsigned short* attn_h = (unsigned short*)(ws + 1310720);  // 524288 us
  unsigned short* attn_l = (unsigned short*)(ws + 1572864);  // 524288 us
  unsigned short* Xh     = (unsigned short*)(ws + 1835008);  // 1572864 us
  unsigned short* Xl     = (unsigned short*)(ws + 2621440);  // 1572864 us
  unsigned short* Wh     = (unsigned short*)(ws + 3407872);  // 786432 us
  unsigned short* Wl     = (unsigned short*)(ws + 3801088);  // 786432 us
  unsigned short* Owh    = (unsigned short*)(ws + 4194304);  // 262144 us
  unsigned short* Owl    = (unsigned short*)(ws + 4325376);  // 262144 us

  prep_kernel<<<2560, 256, 0, stream>>>(query, key, value, W, out_w,
                                        Xh, Xl, Wh, Wl, Owh, Owl);
  projmm_kernel<<<dim3(48, 16), 256, 0, stream>>>(Xh, Xl, Wh, Wl, pb,
                                                  qh, kh, vh);
  score_kernel<<<1024, 256, 0, stream>>>(qh, kh, vh, cbias, attn_h, attn_l);
  outmm_kernel<<<dim3(16, 16), 256, 0, stream>>>(attn_h, attn_l, Owh, Owl,
                                                 out_b, out);
}

// Round 14
// 176.012 us; speedup vs baseline: 1.6208x; 1.0178x over previous
//
#include <hip/hip_runtime.h>
#include <math.h>

#define SCALING 0.125f

typedef __attribute__((ext_vector_type(8))) short short8;
typedef __attribute__((ext_vector_type(4))) float f32x4;

// round-to-nearest-even fp32 -> bf16
static __device__ __forceinline__ unsigned short bf16r(float x) {
  unsigned int u = __float_as_uint(x);
  u += 0x7fffu + ((u >> 16) & 1u);
  return (unsigned short)(u >> 16);
}
static __device__ __forceinline__ float bf16f(unsigned short h) {
  return __uint_as_float(((unsigned int)h) << 16);
}
// pack two fp32 -> bf16x2 via v_perm_b32 merge
static __device__ __forceinline__ unsigned int pk_bf16(float lo, float hi) {
  unsigned int ua = __float_as_uint(lo);
  unsigned int ub = __float_as_uint(hi);
  ua += 0x7fffu + ((ua >> 16) & 1u);
  ub += 0x7fffu + ((ub >> 16) & 1u);
  return __builtin_amdgcn_perm(ub, ua, 0x07060302u);
}
// fp32x4 -> bf16 hi + residual lo
static __device__ __forceinline__ void split4(float4 x, ushort4& h, ushort4& l) {
  h.x = bf16r(x.x); l.x = bf16r(x.x - bf16f(h.x));
  h.y = bf16r(x.y); l.y = bf16r(x.y - bf16f(h.y));
  h.z = bf16r(x.z); l.z = bf16r(x.z - bf16f(h.z));
  h.w = bf16r(x.w); l.w = bf16r(x.w - bf16f(h.w));
}
union U4S8 { uint4 u; short8 s; };

// async global->LDS, 16B per lane (wave-uniform LDS base + lane*16; per-lane
// global address). Tracked by vmcnt; __syncthreads drains it (m97 semantics).
static __device__ __forceinline__ void gload16(const unsigned short* g,
                                               unsigned short* l) {
  __builtin_amdgcn_global_load_lds(
      (const __attribute__((address_space(1))) void*)(g),
      (__attribute__((address_space(3))) void*)(l), 16, 0, 0);
}

// ---------------------------------------------------------------------------
// Kernel P: one-shot hi/lo bf16 split of all loop-invariant GEMM operands.
// R3-verbatim.
// ---------------------------------------------------------------------------
__global__ __launch_bounds__(256)
void prep_kernel(const float* __restrict__ query,
                 const float* __restrict__ key,
                 const float* __restrict__ value,
                 const float* __restrict__ W,
                 const float* __restrict__ out_w,
                 unsigned short* __restrict__ Xh,
                 unsigned short* __restrict__ Xl,
                 unsigned short* __restrict__ Wh,
                 unsigned short* __restrict__ Wl,
                 unsigned short* __restrict__ Owh,
                 unsigned short* __restrict__ Owl) {
  const int t = blockIdx.x * 256 + threadIdx.x;  // 0..655359
  const int e = t * 4;
  const float* __restrict__ src;
  unsigned short *dh, *dl;
  if (e < 1572864) {               // query|key|value: 3 x 524288 floats
    const int g = e >> 19, j = e & 524287;
    src = (g == 0 ? query : g == 1 ? key : value) + j;
    dh = Xh + e; dl = Xl + e;
  } else if (e < 2359296) {        // W: 1536x512
    const int j = e - 1572864;
    src = W + j; dh = Wh + j; dl = Wl + j;
  } else {                         // out_w: 512x512
    const int j = e - 2359296;
    src = out_w + j; dh = Owh + j; dl = Owl + j;
  }
  const float4 v = *(const float4*)src;
  ushort4 hh, ll;
  split4(v, hh, ll);
  *(ushort4*)dh = hh;
  *(ushort4*)dl = ll;
}

// ---------------------------------------------------------------------------
// Kernel A v6: R9-verbatim (gload_lds direct staging, double buffer, one
// barrier per K-step, rule-#21 both-sides swizzle). Measured best.
// ---------------------------------------------------------------------------
__global__ __launch_bounds__(256)
void projmm_kernel(const unsigned short* __restrict__ Xh,
                   const unsigned short* __restrict__ Xl,
                   const unsigned short* __restrict__ Wh,
                   const unsigned short* __restrict__ Wl,
                   const float* __restrict__ bias,
                   float* __restrict__ qh, float* __restrict__ kh,
                   unsigned short* __restrict__ vh) {
  __shared__ __align__(16) unsigned short S[2][12288];
  const int n0 = blockIdx.x * 32;  // 0..1504
  const int g = n0 >> 9;           // 0=q,1=k,2=v (32-tiles never straddle 512)
  const unsigned short* __restrict__ Xgh = Xh + g * 524288;
  const unsigned short* __restrict__ Xgl = Xl + g * 524288;
  const int m0 = blockIdx.y * 64;
  const int tid = threadIdx.x;
  const int w = tid >> 6, lane = tid & 63;
  const int quad = lane >> 4, n15 = lane & 15;
  const int lrow = lane >> 3;                       // 0..7 (chunk-local row)
  const int colOff = ((lane & 7) ^ lrow) * 8;       // inverse-swz source col

  // per-wave 6 staging chunks: global base (sans k0) + LDS offset
  const unsigned short* gb[6];
  int lo[6];
#pragma unroll
  for (int j = 0; j < 6; ++j) {
    const int c = w * 6 + j;
    const unsigned short* gsrc;
    int off, grow;
    if (c < 8)       { gsrc = Xgh; off = c * 512;              grow = m0 + c * 8; }
    else if (c < 16) { gsrc = Xgl; off = 4096 + (c - 8) * 512;  grow = m0 + (c - 8) * 8; }
    else if (c < 20) { gsrc = Wh;  off = 8192 + (c - 16) * 512; grow = n0 + (c - 16) * 8; }
    else             { gsrc = Wl;  off = 10240 + (c - 20) * 512; grow = n0 + (c - 20) * 8; }
    gb[j] = gsrc + (size_t)(grow + lrow) * 512 + colOff;
    lo[j] = off;
  }

  f32x4 acc[2];
#pragma unroll
  for (int nt = 0; nt < 2; ++nt) acc[nt] = (f32x4){0.f, 0.f, 0.f, 0.f};

  // prologue: stage k-tile 0 into side 0
#pragma unroll
  for (int j = 0; j < 6; ++j) gload16(gb[j], &S[0][lo[j]]);
  __syncthreads();

  const int rA = w * 16 + n15;
  const int swz = n15 & 7;
  int side = 0;
  for (int k0 = 0; k0 < 512; k0 += 64) {
    if (k0 + 64 < 512) {
      const int ns = side ^ 1;
#pragma unroll
      for (int j = 0; j < 6; ++j) gload16(gb[j] + k0 + 64, &S[ns][lo[j]]);
    }
#pragma unroll
    for (int kk = 0; kk < 2; ++kk) {
      const int gA0 = ((kk * 4 + quad) ^ swz) * 8;
      short8 ah = *(const short8*)&S[side][rA * 64 + gA0];
      short8 al = *(const short8*)&S[side][4096 + rA * 64 + gA0];
#pragma unroll
      for (int nt = 0; nt < 2; ++nt) {
        const int rB = nt * 16 + n15;
        short8 bh = *(const short8*)&S[side][8192 + rB * 64 + gA0];
        short8 bl = *(const short8*)&S[side][10240 + rB * 64 + gA0];
        acc[nt] = __builtin_amdgcn_mfma_f32_16x16x32_bf16(ah, bh, acc[nt], 0, 0, 0);
        acc[nt] = __builtin_amdgcn_mfma_f32_16x16x32_bf16(ah, bl, acc[nt], 0, 0, 0);
        acc[nt] = __builtin_amdgcn_mfma_f32_16x16x32_bf16(al, bh, acc[nt], 0, 0, 0);
      }
    }
    if (k0 + 64 < 512) {
      __syncthreads();  // drains vmcnt (stage done) + all reads of 'side' done
      side ^= 1;
    }
  }

#pragma unroll
  for (int nt = 0; nt < 2; ++nt) {
    const int j = n0 + nt * 16 + n15;
    const int jj = j & 511;
    const int head = jj >> 6;
    const int hd = jj & 63;
    const float bj = bias[j];
#pragma unroll
    for (int r = 0; r < 4; ++r) {
      const int row = m0 + w * 16 + quad * 4 + r;
      const int t = row >> 3;
      const int batch = row & 7;
      const int i = batch * 8 + head;
      const int idx = ((i << 7) + t) * 64 + hd;
      const float val = acc[nt][r] + bj;
      if (g == 0)      qh[idx] = val * SCALING;
      else if (g == 1) kh[idx] = val;
      else             vh[idx] = bf16r(val);
    }
  }
}

// ---------------------------------------------------------------------------
// Kernel B v8: R13 with the fused tail's TWO heads processed INTERLEAVED:
// both softmax shuffle chains issued together (two independent DS chains
// overlap instead of serializing), then both bmm load streams together
// with 8 partial accumulators (~32 q-loads in flight vs 16). Same fp32
// reassociation class as R13; error stays bf16-quantization-dominated.
// ---------------------------------------------------------------------------
__global__ __launch_bounds__(256, 2)
void score_kernel(const float* __restrict__ qh,
                  const float* __restrict__ kh,
                  const unsigned short* __restrict__ vh,
                  const float* __restrict__ cbias,
                  unsigned short* __restrict__ attn_h,
                  unsigned short* __restrict__ attn_l) {
  __shared__ __align__(16) unsigned short Ks[2][128 * 72];
  __shared__ __align__(16) unsigned short Vs[2][128 * 72];
  __shared__ float rowS[8 * 128];  // fused rows, then softmax weights

  const int d = blockIdx.x;
  const int ab = ((d & 7) << 7) | (d >> 3);  // batch = d&7 -> XCD-local batch
  const int batch = ab >> 7;
  const int a = ab & 127;
  const int tid = threadIdx.x;
  const int w = tid >> 6;
  const int lane = tid & 63;
  const int quad = lane >> 4;
  const int n15 = lane & 15;
  const int col8 = (tid & 7) * 8;

  // bias fragment preload (head-invariant coords; verified mapping) — NT loads
  const float* __restrict__ bp = cbias + (size_t)ab * 16384;
  f32x4 biasReg[8][2];
#pragma unroll
  for (int ic = 0; ic < 8; ++ic)
#pragma unroll
    for (int jb = 0; jb < 2; ++jb) {
      const int b = w * 32 + jb * 16 + n15;
      biasReg[ic][jb] = __builtin_nontemporal_load(
          (const f32x4*)&bp[b * 128 + ic * 16 + quad * 4]);
    }

  // ---- prologue: stage head 0 into buffer 0 ----
  {
    const int i = batch * 8;
    const float* __restrict__ kb = kh + (size_t)i * 8192;
    const uint4* __restrict__ vb4 = (const uint4*)(vh + (size_t)i * 8192);
    const float* __restrict__ qa = qh + ((size_t)i * 128 + a) * 64;
    f32x4 q0 = *(const f32x4*)&qa[col8];
    f32x4 q1 = *(const f32x4*)&qa[col8 + 4];
#pragma unroll
    for (int j = 0; j < 4; ++j) {
      const int gg = j * 256 + tid;
      const int row = gg >> 3;
      *(uint4*)&Vs[0][row * 72 + col8] = vb4[gg];
      f32x4 k0 = *(const f32x4*)&kb[8 * gg];
      f32x4 k1 = *(const f32x4*)&kb[8 * gg + 4];
      k0 *= q0;
      k1 *= q1;
      uint4 pk;
      pk.x = pk_bf16(k0[0], k0[1]); pk.y = pk_bf16(k0[2], k0[3]);
      pk.z = pk_bf16(k1[0], k1[1]); pk.w = pk_bf16(k1[2], k1[3]);
      *(uint4*)&Ks[0][row * 72 + col8] = pk;
    }
  }
  __syncthreads();

  for (int h = 0; h < 8; ++h) {
    const int buf = h & 1;
    const int i = batch * 8 + h;

    // ---- issue next head's global loads (in flight during MFMA)
    uint4 vreg[4];
    f32x4 kreg[4][2];
    f32x4 qn0, qn1;
    if (h < 7) {
      const int in = i + 1;
      const float* __restrict__ kb = kh + (size_t)in * 8192;
      const uint4* __restrict__ vb4 = (const uint4*)(vh + (size_t)in * 8192);
      const float* __restrict__ qa = qh + ((size_t)in * 128 + a) * 64;
      qn0 = *(const f32x4*)&qa[col8];
      qn1 = *(const f32x4*)&qa[col8 + 4];
#pragma unroll
      for (int j = 0; j < 4; ++j) {
        const int gg = j * 256 + tid;
        vreg[j] = vb4[gg];
        kreg[j][0] = *(const f32x4*)&kb[8 * gg];
        kreg[j][1] = *(const f32x4*)&kb[8 * gg + 4];
      }
    }

    // ---- B-fragments from Ks[buf]
    short8 bf[2][2];
#pragma unroll
    for (int jb = 0; jb < 2; ++jb)
#pragma unroll
      for (int kk = 0; kk < 2; ++kk)
        bf[jb][kk] = *(const short8*)&Ks[buf][(w * 32 + jb * 16 + n15) * 72 +
                                             kk * 32 + quad * 8];

    // ---- MFMA: S^T[c,b]; bias as C-init (R1-verified)
    f32x4 acc[8][2];
#pragma unroll
    for (int ic = 0; ic < 8; ++ic) {
      short8 a0 = *(const short8*)&Vs[buf][(ic * 16 + n15) * 72 + quad * 8];
      short8 a1 = *(const short8*)&Vs[buf][(ic * 16 + n15) * 72 + 32 + quad * 8];
      acc[ic][0] = __builtin_amdgcn_mfma_f32_16x16x32_bf16(a0, bf[0][0], biasReg[ic][0], 0, 0, 0);
      acc[ic][0] = __builtin_amdgcn_mfma_f32_16x16x32_bf16(a1, bf[0][1], acc[ic][0], 0, 0, 0);
      acc[ic][1] = __builtin_amdgcn_mfma_f32_16x16x32_bf16(a0, bf[1][0], biasReg[ic][1], 0, 0, 0);
      acc[ic][1] = __builtin_amdgcn_mfma_f32_16x16x32_bf16(a1, bf[1][1], acc[ic][1], 0, 0, 0);
    }

    // ---- pack + store next head's staging into the other buffer
    if (h < 7) {
      const int nb = buf ^ 1;
#pragma unroll
      for (int j = 0; j < 4; ++j) {
        const int gg = j * 256 + tid;
        const int row = gg >> 3;
        *(uint4*)&Vs[nb][row * 72 + col8] = vreg[j];
        kreg[j][0] *= qn0;
        kreg[j][1] *= qn1;
        uint4 pk;
        pk.x = pk_bf16(kreg[j][0][0], kreg[j][0][1]);
        pk.y = pk_bf16(kreg[j][0][2], kreg[j][0][3]);
        pk.z = pk_bf16(kreg[j][1][0], kreg[j][1][1]);
        pk.w = pk_bf16(kreg[j][1][2], kreg[j][1][3]);
        *(uint4*)&Ks[nb][row * 72 + col8] = pk;
      }
    }

    // ---- epilogue: mean/max over c (bias already in acc) -> rowS (LDS)
    float fsum[2] = {0.f, 0.f};
    float fmx[2] = {-INFINITY, -INFINITY};
#pragma unroll
    for (int ic = 0; ic < 8; ++ic)
#pragma unroll
      for (int jb = 0; jb < 2; ++jb) {
        const float v0 = acc[ic][jb][0];
        const float v1 = acc[ic][jb][1];
        const float v2 = acc[ic][jb][2];
        const float v3 = acc[ic][jb][3];
        fsum[jb] += (v0 + v1) + (v2 + v3);
        fmx[jb] = fmaxf(fmx[jb], fmaxf(fmaxf(v0, v1), fmaxf(v2, v3)));
      }
#pragma unroll
    for (int off = 16; off <= 32; off <<= 1) {
#pragma unroll
      for (int jb = 0; jb < 2; ++jb) {
        fsum[jb] += __shfl_xor(fsum[jb], off, 64);
        fmx[jb] = fmaxf(fmx[jb], __shfl_xor(fmx[jb], off, 64));
      }
    }
    if (quad == 0) {
      rowS[h * 128 + w * 32 + n15] = fsum[0] * (1.0f / 128.0f) + fmx[0];
      rowS[h * 128 + w * 32 + 16 + n15] = fsum[1] * (1.0f / 128.0f) + fmx[1];
    }

    __syncthreads();  // h's reads done; h's stores visible; rowS visible
  }

  // ---- fused tail: wave w owns heads h0=2w, h1=2w+1, fully interleaved
  {
    const int h0 = w * 2, h1 = h0 + 1;
    const int i0 = batch * 8 + h0, i1 = i0 + 1;
    // softmax: two independent shuffle chains, issued together
    float f00 = rowS[h0 * 128 + lane], f01 = rowS[h0 * 128 + 64 + lane];
    float f10 = rowS[h1 * 128 + lane], f11 = rowS[h1 * 128 + 64 + lane];
    float m0 = fmaxf(f00, f01);
    float m1 = fmaxf(f10, f11);
#pragma unroll
    for (int off = 32; off >= 1; off >>= 1) {
      m0 = fmaxf(m0, __shfl_xor(m0, off, 64));
      m1 = fmaxf(m1, __shfl_xor(m1, off, 64));
    }
    const float e00 = expf(f00 - m0), e01 = expf(f01 - m0);
    const float e10 = expf(f10 - m1), e11 = expf(f11 - m1);
    float s0 = e00 + e01;
    float s1 = e10 + e11;
#pragma unroll
    for (int off = 32; off >= 1; off >>= 1) {
      s0 += __shfl_xor(s0, off, 64);
      s1 += __shfl_xor(s1, off, 64);
    }
    const float inv0 = 1.0f / s0, inv1 = 1.0f / s1;
    rowS[h0 * 128 + lane] = e00 * inv0;       // same wave produces &
    rowS[h0 * 128 + 64 + lane] = e01 * inv0;  // consumes: no barrier
    rowS[h1 * 128 + lane] = e10 * inv1;
    rowS[h1 * 128 + 64 + lane] = e11 * inv1;
    const float* __restrict__ qp0 = qh + (size_t)i0 * 8192 + lane;
    const float* __restrict__ qp1 = qh + (size_t)i1 * 8192 + lane;
    // bmm: both heads' load streams together; 8 partials (~32 loads in
    // flight), serial fma chain per partial = 32.
    float p00 = 0.f, p01 = 0.f, p02 = 0.f, p03 = 0.f;
    float p10 = 0.f, p11 = 0.f, p12 = 0.f, p13 = 0.f;
#pragma unroll 4
    for (int b = 0; b < 128; b += 4) {
      p00 = fmaf(rowS[h0 * 128 + b],     qp0[b * 64],       p00);
      p10 = fmaf(rowS[h1 * 128 + b],     qp1[b * 64],       p10);
      p01 = fmaf(rowS[h0 * 128 + b + 1], qp0[(b + 1) * 64], p01);
      p11 = fmaf(rowS[h1 * 128 + b + 1], qp1[(b + 1) * 64], p11);
      p02 = fmaf(rowS[h0 * 128 + b + 2], qp0[(b + 2) * 64], p02);
      p12 = fmaf(rowS[h1 * 128 + b + 2], qp1[(b + 2) * 64], p12);
      p03 = fmaf(rowS[h0 * 128 + b + 3], qp0[(b + 3) * 64], p03);
      p13 = fmaf(rowS[h1 * 128 + b + 3], qp1[(b + 3) * 64], p13);
    }
    const float acc20 = (p00 + p01) + (p02 + p03);
    const float acc21 = (p10 + p11) + (p12 + p13);
    const size_t idx0 = ((size_t)a * 8 + batch) * 512 + h0 * 64 + lane;
    const size_t idx1 = ((size_t)a * 8 + batch) * 512 + h1 * 64 + lane;
    const unsigned short hi0 = bf16r(acc20);
    const unsigned short hi1 = bf16r(acc21);
    attn_h[idx0] = hi0;
    attn_l[idx0] = bf16r(acc20 - bf16f(hi0));
    attn_h[idx1] = hi1;
    attn_l[idx1] = bf16r(acc21 - bf16f(hi1));
  }
}

// ---------------------------------------------------------------------------
// Kernel D v6: R9-verbatim (gload_lds single-barrier template).
// ---------------------------------------------------------------------------
__global__ __launch_bounds__(256)
void outmm_kernel(const unsigned short* __restrict__ Xah,
                  const unsigned short* __restrict__ Xal,
                  const unsigned short* __restrict__ Owh,
                  const unsigned short* __restrict__ Owl,
                  const float* __restrict__ bias,
                  float* __restrict__ out) {
  __shared__ __align__(16) unsigned short S[2][12288];
  const int n0 = blockIdx.x * 32;  // 0..480
  const int m0 = blockIdx.y * 64;  // 0..960
  const int tid = threadIdx.x;
  const int w = tid >> 6, lane = tid & 63;
  const int quad = lane >> 4, n15 = lane & 15;
  const int lrow = lane >> 3;
  const int colOff = ((lane & 7) ^ lrow) * 8;

  const unsigned short* gb[6];
  int lo[6];
#pragma unroll
  for (int j = 0; j < 6; ++j) {
    const int c = w * 6 + j;
    const unsigned short* gsrc;
    int off, grow;
    if (c < 8)       { gsrc = Xah; off = c * 512;               grow = m0 + c * 8; }
    else if (c < 16) { gsrc = Xal; off = 4096 + (c - 8) * 512;   grow = m0 + (c - 8) * 8; }
    else if (c < 20) { gsrc = Owh; off = 8192 + (c - 16) * 512;  grow = n0 + (c - 16) * 8; }
    else             { gsrc = Owl; off = 10240 + (c - 20) * 512; grow = n0 + (c - 20) * 8; }
    gb[j] = gsrc + (size_t)(grow + lrow) * 512 + colOff;
    lo[j] = off;
  }

  f32x4 acc[2];
#pragma unroll
  for (int nt = 0; nt < 2; ++nt) acc[nt] = (f32x4){0.f, 0.f, 0.f, 0.f};

#pragma unroll
  for (int j = 0; j < 6; ++j) gload16(gb[j], &S[0][lo[j]]);
  __syncthreads();

  const int rA = w * 16 + n15;
  const int swz = n15 & 7;
  int side = 0;
  for (int k0 = 0; k0 < 512; k0 += 64) {
    if (k0 + 64 < 512) {
      const int ns = side ^ 1;
#pragma unroll
      for (int j = 0; j < 6; ++j) gload16(gb[j] + k0 + 64, &S[ns][lo[j]]);
    }
#pragma unroll
    for (int kk = 0; kk < 2; ++kk) {
      const int gA0 = ((kk * 4 + quad) ^ swz) * 8;
      short8 ah = *(const short8*)&S[side][rA * 64 + gA0];
      short8 al = *(const short8*)&S[side][4096 + rA * 64 + gA0];
#pragma unroll
      for (int nt = 0; nt < 2; ++nt) {
        const int rB = nt * 16 + n15;
        short8 bh = *(const short8*)&S[side][8192 + rB * 64 + gA0];
        short8 bl = *(const short8*)&S[side][10240 + rB * 64 + gA0];
        acc[nt] = __builtin_amdgcn_mfma_f32_16x16x32_bf16(ah, bh, acc[nt], 0, 0, 0);
        acc[nt] = __builtin_amdgcn_mfma_f32_16x16x32_bf16(ah, bl, acc[nt], 0, 0, 0);
        acc[nt] = __builtin_amdgcn_mfma_f32_16x16x32_bf16(al, bh, acc[nt], 0, 0, 0);
      }
    }
    if (k0 + 64 < 512) {
      __syncthreads();
      side ^= 1;
    }
  }

#pragma unroll
  for (int nt = 0; nt < 2; ++nt) {
    const int j = n0 + nt * 16 + n15;
    const float bj = bias[j];
#pragma unroll
    for (int r = 0; r < 4; ++r) {
      const int row = m0 + w * 16 + quad * 4 + r;
      out[(size_t)row * 512 + j] = acc[nt][r] + bj;
    }
  }
}

extern "C" void kernel_launch(void* const* d_in, const int* in_sizes, int n_in,
                              void* d_out, int out_size, void* d_ws,
                              size_t ws_size, hipStream_t stream) {
  const float* query = (const float*)d_in[0];
  const float* key   = (const float*)d_in[1];
  const float* value = (const float*)d_in[2];
  const float* cbias = (const float*)d_in[3];
  const float* W     = (const float*)d_in[4];
  const float* pb    = (const float*)d_in[5];
  const float* out_w = (const float*)d_in[6];
  const float* out_b = (const float*)d_in[7];
  float* out = (float*)d_out;

  float* ws = (float*)d_ws;
  float* qh = ws;                                            // 524288 f
  float* kh = ws + 524288;                                   // 524288 f
  unsigned short* vh     = (unsigned short*)(ws + 1048576);  // 524288 us
  unsigned short* attn_h = (unsigned short*)(ws + 1310720);  // 524288 us
  unsigned short* attn_l = (unsigned short*)(ws + 1572864);  // 524288 us
  unsigned short* Xh     = (unsigned short*)(ws + 1835008);  // 1572864 us
  unsigned short* Xl     = (unsigned short*)(ws + 2621440);  // 1572864 us
  unsigned short* Wh     = (unsigned short*)(ws + 3407872);  // 786432 us
  unsigned short* Wl     = (unsigned short*)(ws + 3801088);  // 786432 us
  unsigned short* Owh    = (unsigned short*)(ws + 4194304);  // 262144 us
  unsigned short* Owl    = (unsigned short*)(ws + 4325376);  // 262144 us

  prep_kernel<<<2560, 256, 0, stream>>>(query, key, value, W, out_w,
                                        Xh, Xl, Wh, Wl, Owh, Owl);
  projmm_kernel<<<dim3(48, 16), 256, 0, stream>>>(Xh, Xl, Wh, Wl, pb,
                                                  qh, kh, vh);
  score_kernel<<<1024, 256, 0, stream>>>(qh, kh, vh, cbias, attn_h, attn_l);
  outmm_kernel<<<dim3(16, 16), 256, 0, stream>>>(attn_h, attn_l, Owh, Owl,
                                                 out_b, out);
}